// Round 5
// baseline (1414.605 us; speedup 1.0000x reference)
//
#include <hip/hip_runtime.h>
#include <hip/hip_bf16.h>

// ---------- types ----------
using short8  = __attribute__((ext_vector_type(8))) short;
using ushort8 = __attribute__((ext_vector_type(8))) unsigned short;
using us4     = __attribute__((ext_vector_type(4))) unsigned short;
using f32x4   = __attribute__((ext_vector_type(4))) float;

#define GLB(p)  ((const __attribute__((address_space(1))) void*)(p))
#define LDSP(p) ((__attribute__((address_space(3))) void*)(p))

static __device__ __forceinline__ unsigned short f2bf(float f) {
    union { float f; unsigned u; } v; v.f = f;
    unsigned u = v.u;
    u += 0x7fffu + ((u >> 16) & 1u);   // round-to-nearest-even
    return (unsigned short)(u >> 16);
}

// ---------- problem constants ----------
#define K_DIM 2048
#define N_DIM 2048
#define M_TOTAL 26112
#define N_GROUPS 8
#define NCONV 52          // converter blocks 0..51
#define NGEMM 204         // gemm blocks 52..255, 4 tiles each (816 = 204*4)
#define NTASKS 880        // 8 kc * (102 A-panels + 8 B-groups)
#define NFLAGS 880        // aflags[102*8] then bflags[8*8]

// ---------- sync helpers ----------
#define PBAR() __builtin_amdgcn_s_barrier()
#define LGKM0() asm volatile("s_waitcnt lgkmcnt(0)" ::: "memory")
#define VMC(n)  asm volatile("s_waitcnt vmcnt(" #n ")" ::: "memory")

static __device__ __forceinline__ void wait_flag(const unsigned* f) {
    while (__hip_atomic_load(f, __ATOMIC_ACQUIRE, __HIP_MEMORY_SCOPE_AGENT) == 0u)
        __builtin_amdgcn_s_sleep(32);
}

// ---------- GEMM staging / MFMA macros (proven round-4 structure) ----------
#define ST_A(BUF, H, L, TT)                                                        \
    __builtin_amdgcn_global_load_lds(                                              \
        GLB(aSt + (long)((H) * 128 + (L) * 64) * K_DIM + (TT) * 64),               \
        LDSP(lds + (BUF) * 32768 + (H) * 8192 + (L) * 4096 + w * 512), 16, 0, 0)
#define ST_B(BUF, H, L, TT)                                                        \
    __builtin_amdgcn_global_load_lds(                                              \
        GLB(bSt + (long)((H) * 128 + (L) * 64) * K_DIM + (TT) * 64),               \
        LDSP(lds + (BUF) * 32768 + 16384 + (H) * 8192 + (L) * 4096 + w * 512), 16, 0, 0)

#define MMQ(MH, NH, AV, BV)                                                        \
    _Pragma("unroll") for (int i = 0; i < 4; ++i)                                  \
    _Pragma("unroll") for (int j = 0; j < 2; ++j)                                  \
        acc[(MH) * 4 + i][(NH) * 2 + j] = __builtin_amdgcn_mfma_f32_16x16x32_bf16( \
            AV[i], BV[j], acc[(MH) * 4 + i][(NH) * 2 + j], 0, 0, 0);

#define TILE(BUF, T, DO1, DO2)                                                          \
    do {                                                                                \
        const unsigned short* pA = lds + (BUF) * 32768 + wm * 1024 + r16 * 64;          \
        const unsigned short* pB = lds + (BUF) * 32768 + 16384 + wn * 1024 + r16 * 64;  \
        short8 a0[4], a1[4], b00[2], b01[2], b10[2], b11[2];                            \
        /* ph1: read A-h0 + B-h0; stage A(T+1)-h1 -> buf^1; MFMA m0n0 */                \
        _Pragma("unroll") for (int i = 0; i < 4; ++i) {                                 \
            a0[i] = *(const short8*)(pA + i * 2048 + c0 * 8);                           \
            a1[i] = *(const short8*)(pA + i * 2048 + c1 * 8);                           \
        }                                                                               \
        _Pragma("unroll") for (int j = 0; j < 2; ++j) {                                 \
            b00[j] = *(const short8*)(pB + j * 4096 + c0 * 8);                          \
            b01[j] = *(const short8*)(pB + j * 4096 + c1 * 8);                          \
        }                                                                               \
        if (DO1) { ST_A((BUF) ^ 1, 1, 0, (T) + 1); ST_A((BUF) ^ 1, 1, 1, (T) + 1); }    \
        PBAR(); LGKM0();                                                                \
        __builtin_amdgcn_s_setprio(1); MMQ(0, 0, a0, b00); MMQ(0, 0, a1, b01);          \
        __builtin_amdgcn_s_setprio(0); PBAR();                                          \
        /* ph2: read B-h1; stage A(T+2)-h0 -> buf; MFMA m0n1 */                         \
        _Pragma("unroll") for (int j = 0; j < 2; ++j) {                                 \
            b10[j] = *(const short8*)(pB + 8192 + j * 4096 + c0 * 8);                   \
            b11[j] = *(const short8*)(pB + 8192 + j * 4096 + c1 * 8);                   \
        }                                                                               \
        if (DO2) { ST_A((BUF), 0, 0, (T) + 2); ST_A((BUF), 0, 1, (T) + 2); }            \
        PBAR(); LGKM0();                                                                \
        __builtin_amdgcn_s_setprio(1); MMQ(0, 1, a0, b10); MMQ(0, 1, a1, b11);          \
        __builtin_amdgcn_s_setprio(0); PBAR();                                          \
        /* ph3: read A-h1; stage B(T+2)-h0 -> buf; MFMA m1n0 */                         \
        _Pragma("unroll") for (int i = 0; i < 4; ++i) {                                 \
            a0[i] = *(const short8*)(pA + 8192 + i * 2048 + c0 * 8);                    \
            a1[i] = *(const short8*)(pA + 8192 + i * 2048 + c1 * 8);                    \
        }                                                                               \
        if (DO2) { ST_B((BUF), 0, 0, (T) + 2); ST_B((BUF), 0, 1, (T) + 2); }            \
        PBAR(); LGKM0();                                                                \
        __builtin_amdgcn_s_setprio(1); MMQ(1, 0, a0, b00); MMQ(1, 0, a1, b01);          \
        __builtin_amdgcn_s_setprio(0); PBAR();                                          \
        /* ph4: register-only; stage B(T+2)-h1 -> buf; MFMA m1n1 */                     \
        if (DO2) { ST_B((BUF), 1, 0, (T) + 2); ST_B((BUF), 1, 1, (T) + 2); }            \
        __builtin_amdgcn_s_setprio(1); MMQ(1, 1, a0, b10); MMQ(1, 1, a1, b11);          \
        __builtin_amdgcn_s_setprio(0);                                                  \
    } while (0)

// ---------- fused producer/consumer kernel ----------
__global__ __launch_bounds__(512, 2) void fused_kernel(
        const float* __restrict__ A0, const float* __restrict__ A1,
        const float* __restrict__ A2, const float* __restrict__ A3,
        const float* __restrict__ A4, const float* __restrict__ A5,
        const float* __restrict__ A6, const float* __restrict__ A7,
        const float* __restrict__ B,
        unsigned short* __restrict__ Acat, unsigned short* __restrict__ Bt,
        unsigned* __restrict__ flags, float* __restrict__ C) {
    __shared__ unsigned short lds[65536];   // 128 KiB

    int tid = threadIdx.x;
    int l   = tid & 63;
    int w   = tid >> 6;

    if (blockIdx.x < NCONV) {
        // ================= CONVERTER =================
        // 880 tasks, kc-major: task T -> kc = T/110, idx = T%110 (<102: A panel, else B group)
        int j = blockIdx.x;
        for (int T = j; T < NTASKS; T += NCONV) {
            int kc  = T / 110;
            int idx = T - kc * 110;
            if (idx < 102) {
                // --- A panel idx, K-chunk kc: 256 rows x 256 k, fp32 -> bf16 ---
                const float* src; int gr0;
                if      (idx < 16) { src = A0; gr0 = 0;     }
                else if (idx < 24) { src = A1; gr0 = 4096;  }
                else if (idx < 28) { src = A2; gr0 = 6144;  }
                else if (idx < 60) { src = A3; gr0 = 7168;  }
                else if (idx < 62) { src = A4; gr0 = 15360; }
                else if (idx < 74) { src = A5; gr0 = 15872; }
                else if (idx < 98) { src = A6; gr0 = 18944; }
                else               { src = A7; gr0 = 25088; }
                long srow0 = (long)idx * 256 - gr0;
#pragma unroll 4
                for (int i = 0; i < 32; ++i) {
                    int r = i * 8 + w;
                    float4 v = *(const float4*)(src + (srow0 + r) * K_DIM + kc * 256 + l * 4);
                    us4 o = { f2bf(v.x), f2bf(v.y), f2bf(v.z), f2bf(v.w) };
                    *(us4*)(Acat + (long)(idx * 256 + r) * K_DIM + kc * 256 + l * 4) = o;
                }
                __syncthreads();
                if (tid == 0)
                    __hip_atomic_store(&flags[idx * 8 + kc], 1u, __ATOMIC_RELEASE,
                                       __HIP_MEMORY_SCOPE_AGENT);
            } else {
                // --- B group g, K-chunk kc: transpose 256k x 256n -> Bt[n][k] bf16 ---
                int g = idx - 102;
                float* ldsf = (float*)lds;
                for (int st = 0; st < 4; ++st) {
#pragma unroll
                    for (int i = 0; i < 8; ++i) {
                        int kr = i * 8 + w;
                        float4 v = *(const float4*)(B + (long)(kc * 256 + st * 64 + kr) * N_DIM +
                                                    g * 256 + l * 4);
                        *(float4*)(ldsf + kr * 260 + l * 4) = v;
                    }
                    __syncthreads();
                    int n = tid >> 1, jo = (tid & 1) * 32;
                    unsigned short* dst = Bt + (long)(g * 256 + n) * K_DIM + kc * 256 + st * 64 + jo;
#pragma unroll
                    for (int jj = 0; jj < 4; ++jj) {
                        ushort8 o;
#pragma unroll
                        for (int q = 0; q < 8; ++q) o[q] = f2bf(ldsf[(jo + jj * 8 + q) * 260 + n]);
                        *(ushort8*)(dst + jj * 8) = o;
                    }
                    __syncthreads();
                }
                __syncthreads();
                if (tid == 0)
                    __hip_atomic_store(&flags[816 + g * 8 + kc], 1u, __ATOMIC_RELEASE,
                                       __HIP_MEMORY_SCOPE_AGENT);
            }
        }
        return;
    }

    // ================= GEMM (persistent, 4 tiles) =================
    int b  = blockIdx.x - NCONV;    // 0..203
    int wm = w >> 2;                // 0..1
    int wn = w & 3;                 // 0..3
    int r16 = l & 15, kc_ = l >> 4, x = l & 7;
    int c0 = kc_ ^ x;               // swizzled chunk, k-step 0
    int c1 = (4 + kc_) ^ x;         // swizzled chunk, k-step 1
    int srow = tid >> 3;
    int sq   = (tid & 7) ^ (srow & 7);

#pragma unroll 1
    for (int s = 0; s < 4; ++s) {
        int t_lin = s * NGEMM + b;          // 0..815
        int mt = t_lin >> 3, nt = t_lin & 7;
        int m0 = mt * 256, n0 = nt * 256;

        const unsigned short* aSt = Acat + (long)(m0 + srow) * K_DIM + sq * 8;
        const unsigned short* bSt = Bt   + (long)(n0 + srow) * K_DIM + sq * 8;
        const unsigned* af = flags + mt * 8;
        const unsigned* bf = flags + 816 + nt * 8;

        wait_flag(af); wait_flag(bf);       // K-chunk 0 ready

        f32x4 acc[8][4] = {};

        // prologue: tile0 full (8) + tile1 A0,B0,B1 (6); wait tile0 (vmcnt 6)
        ST_A(0, 0, 0, 0); ST_A(0, 0, 1, 0); ST_A(0, 1, 0, 0); ST_A(0, 1, 1, 0);
        ST_B(0, 0, 0, 0); ST_B(0, 0, 1, 0); ST_B(0, 1, 0, 0); ST_B(0, 1, 1, 0);
        ST_A(1, 0, 0, 1); ST_A(1, 0, 1, 1);
        ST_B(1, 0, 0, 1); ST_B(1, 0, 1, 1); ST_B(1, 1, 0, 1); ST_B(1, 1, 1, 1);
        VMC(6); PBAR();

#pragma unroll 1
        for (int t = 0; t < 30; t += 2) {
            if ((t & 3) == 2) {             // about to stage K-tiles (t+2)..(t+5)
                int kc2 = (t + 2) >> 2;
                wait_flag(af + kc2); wait_flag(bf + kc2);
            }
            TILE(0, t, 1, 1);     VMC(6); PBAR();
            TILE(1, t + 1, 1, 1); VMC(6); PBAR();
        }
        TILE(0, 30, 1, 0); VMC(0); PBAR();
        TILE(1, 31, 0, 0);

        // epilogue: C/D layout col=lane&15, row=(lane>>4)*4+q
        int orow = m0 + wm * 16 + (l >> 4) * 4;
        int ocol = n0 + wn * 16 + (l & 15);
#pragma unroll
        for (int i = 0; i < 8; ++i)
#pragma unroll
            for (int jj = 0; jj < 4; ++jj)
#pragma unroll
                for (int q = 0; q < 4; ++q)
                    C[(long)(orow + i * 32 + q) * N_DIM + (ocol + jj * 64)] = acc[i][jj][q];
        // LDS safe for next s: all waves passed ph3's barrier of tile 31 (ph4 reads no LDS)
    }
}

// ---------- fallback: correct (slow) fp32 tiled GEMM, used only if ws too small ----------
__global__ void naive_gemm_kernel(const float* __restrict__ A, const float* __restrict__ B,
                                  float* __restrict__ C, int M) {
    __shared__ float As[16][16];
    __shared__ float Bs[16][17];
    int tx = threadIdx.x, ty = threadIdx.y;
    int row = blockIdx.y * 16 + ty;
    int col = blockIdx.x * 16 + tx;
    float s = 0.f;
    for (int k0 = 0; k0 < K_DIM; k0 += 16) {
        As[ty][tx] = A[(long)row * K_DIM + k0 + tx];
        Bs[ty][tx] = B[(long)(k0 + ty) * N_DIM + col];
        __syncthreads();
#pragma unroll
        for (int t = 0; t < 16; ++t) s += As[ty][t] * Bs[t][tx];
        __syncthreads();
    }
    C[(long)row * N_DIM + col] = s;
}

// ---------- host launcher ----------
extern "C" void kernel_launch(void* const* d_in, const int* in_sizes, int n_in,
                              void* d_out, int out_size, void* d_ws, size_t ws_size,
                              hipStream_t stream) {
    static const int g_m[N_GROUPS]   = {4096, 2048, 1024, 8192, 512, 3072, 6144, 1024};
    static const int g_off[N_GROUPS] = {0, 4096, 6144, 7168, 15360, 15872, 18944, 25088};

    float* C = (float*)d_out;
    const size_t acat_elems = (size_t)M_TOTAL * K_DIM;
    const size_t bt_elems   = (size_t)N_DIM * K_DIM;
    const size_t need = (acat_elems + bt_elems) * 2 + NFLAGS * 4;

    if (ws_size >= need) {
        unsigned short* Acat = (unsigned short*)d_ws;
        unsigned short* Bt   = Acat + acat_elems;
        unsigned* flags      = (unsigned*)(Bt + bt_elems);

        hipMemsetAsync(flags, 0, NFLAGS * 4, stream);

        fused_kernel<<<NCONV + NGEMM, 512, 0, stream>>>(
            (const float*)d_in[0], (const float*)d_in[1], (const float*)d_in[2],
            (const float*)d_in[3], (const float*)d_in[4], (const float*)d_in[5],
            (const float*)d_in[6], (const float*)d_in[7], (const float*)d_in[8],
            Acat, Bt, flags, C);
    } else {
        for (int g = 0; g < N_GROUPS; ++g)
            naive_gemm_kernel<<<dim3(N_DIM / 16, g_m[g] / 16), dim3(16, 16), 0, stream>>>(
                (const float*)d_in[g], (const float*)d_in[8], C + (size_t)g_off[g] * N_DIM,
                g_m[g]);
    }
}

// Round 6
// 357.784 us; speedup vs baseline: 3.9538x; 3.9538x over previous
//
#include <hip/hip_runtime.h>
#include <hip/hip_bf16.h>

// ---------- types ----------
using short8  = __attribute__((ext_vector_type(8))) short;
using ushort8 = __attribute__((ext_vector_type(8))) unsigned short;
using f32x4   = __attribute__((ext_vector_type(4))) float;
using f32x16  = __attribute__((ext_vector_type(16))) float;

#define GLB(p)  ((const __attribute__((address_space(1))) void*)(p))
#define LDSP(p) ((__attribute__((address_space(3))) void*)(p))

static __device__ __forceinline__ unsigned short f2bf(float f) {
    union { float f; unsigned u; } v; v.f = f;
    unsigned u = v.u;
    u += 0x7fffu + ((u >> 16) & 1u);   // round-to-nearest-even
    return (unsigned short)(u >> 16);
}

// ---------- problem constants ----------
#define K_DIM 2048
#define N_DIM 2048
#define M_TOTAL 26112
#define N_GROUPS 8

// ---------- kernel 1: merged convert (B-transpose blocks 0..63, A blocks 64..1695) ----------
__global__ __launch_bounds__(256) void cvt_all(
        const float* __restrict__ A0, const float* __restrict__ A1,
        const float* __restrict__ A2, const float* __restrict__ A3,
        const float* __restrict__ A4, const float* __restrict__ A5,
        const float* __restrict__ A6, const float* __restrict__ A7,
        const float* __restrict__ B,
        unsigned short* __restrict__ Acat, unsigned short* __restrict__ Bt) {
    int b   = blockIdx.x;
    int tid = threadIdx.x;
    if (b < 64) {
        // B [K][N] -> Bt [N][K] bf16, 32-col stripe b, all 64 k-tiles
        __shared__ float t[32][33];
        int tx = tid & 31, ty = tid >> 5;
        for (int by = 0; by < 64; ++by) {
#pragma unroll
            for (int i = 0; i < 32; i += 8)
                t[ty + i][tx] = B[(long)(by * 32 + ty + i) * N_DIM + b * 32 + tx];
            __syncthreads();
#pragma unroll
            for (int i = 0; i < 32; i += 8)
                Bt[(long)(b * 32 + ty + i) * K_DIM + by * 32 + tx] = f2bf(t[tx][ty + i]);
            __syncthreads();
        }
    } else {
        // A groups fp32 -> contiguous bf16 Acat, 16 rows per block
        int ab = b - 64;
        const float* src; int gb;   // group base (in 16-row blocks)
        if      (ab < 256)  { src = A0; gb = 0;    }
        else if (ab < 384)  { src = A1; gb = 256;  }
        else if (ab < 448)  { src = A2; gb = 384;  }
        else if (ab < 960)  { src = A3; gb = 448;  }
        else if (ab < 992)  { src = A4; gb = 960;  }
        else if (ab < 1184) { src = A5; gb = 992;  }
        else if (ab < 1568) { src = A6; gb = 1184; }
        else                { src = A7; gb = 1568; }
        const float* s    = src  + (long)(ab - gb) * 16 * K_DIM;
        unsigned short* d = Acat + (long)ab * 16 * K_DIM;
#pragma unroll 4
        for (int i = 0; i < 16; ++i) {
            long off = (long)i * K_DIM + tid * 8;
            float4 x = *(const float4*)(s + off);
            float4 y = *(const float4*)(s + off + 4);
            ushort8 o;
            o[0] = f2bf(x.x); o[1] = f2bf(x.y); o[2] = f2bf(x.z); o[3] = f2bf(x.w);
            o[4] = f2bf(y.x); o[5] = f2bf(y.y); o[6] = f2bf(y.z); o[7] = f2bf(y.w);
            *(ushort8*)(d + off) = o;
        }
    }
}

// ---------- kernel 2: 256x256 8-phase bf16 GEMM, 32x32x16 MFMA ----------
// C[M][N] fp32 = Acat[M][K] bf16 * Bt[N][K]^T bf16.  BK=64, 8 waves (2Mx4N),
// 128 KiB LDS double buffer, raw s_barrier, counted vmcnt(6) at tile end only,
// XOR-swizzled LDS (pre-swizzled global src + swizzled ds_read; linear gload_lds dest).
// Wave tile 128x64: A m-frags i=0..3 at rows wm*32+i*64 (+l&31); B n-frags j=0..1 at
// cols wn*32+j*128 (+l&31). Frag = 8 contiguous k, chunk = 2s+(l>>5), swizzle ^(l&7).

#define PBAR() __builtin_amdgcn_s_barrier()
#define VMC(n)  asm volatile("s_waitcnt vmcnt(" #n ")" ::: "memory")

#define ST_A(BUF, H, L, TT)                                                        \
    __builtin_amdgcn_global_load_lds(                                              \
        GLB(aSt + (long)((H) * 128 + (L) * 64) * K_DIM + (TT) * 64),               \
        LDSP(lds + (BUF) * 32768 + (H) * 8192 + (L) * 4096 + w * 512), 16, 0, 0)
#define ST_B(BUF, H, L, TT)                                                        \
    __builtin_amdgcn_global_load_lds(                                              \
        GLB(bSt + (long)((H) * 128 + (L) * 64) * K_DIM + (TT) * 64),               \
        LDSP(lds + (BUF) * 32768 + 16384 + (H) * 8192 + (L) * 4096 + w * 512), 16, 0, 0)

#define MFMA32(A, B, Cacc) __builtin_amdgcn_mfma_f32_32x32x16_bf16((A), (B), (Cacc), 0, 0, 0)

// one K-tile (BK=64) = 4 phases. DO1: stage A(T+1)-h1 -> buf^1.
// DO2: stage A(T+2)-h0 (ph2), B(T+2)-h0 (ph3), B(T+2)-h1 (ph4) -> buf.
#define TILE(BUF, T, DO1, DO2)                                                          \
    do {                                                                                \
        const unsigned short* pA = lds + (BUF) * 32768 + (wm * 32 + r32) * 64;          \
        const unsigned short* pB = lds + (BUF) * 32768 + 16384 + (wn * 32 + r32) * 64;  \
        short8 a0[4], a1[4], b0[4], b1[4];                                              \
        /* ph1: read A i=0,1 (8) + B j=0 (4); MFMA (i0,i1)xj0 */                        \
        _Pragma("unroll") for (int s = 0; s < 4; ++s) {                                 \
            a0[s] = *(const short8*)(pA + cs[s] * 8);                                   \
            a1[s] = *(const short8*)(pA + 64 * 64 + cs[s] * 8);                         \
            b0[s] = *(const short8*)(pB + cs[s] * 8);                                   \
        }                                                                               \
        if (DO1) { ST_A((BUF) ^ 1, 1, 0, (T) + 1); ST_A((BUF) ^ 1, 1, 1, (T) + 1); }    \
        PBAR();                                                                         \
        __builtin_amdgcn_s_setprio(1);                                                  \
        _Pragma("unroll") for (int s = 0; s < 4; ++s) {                                 \
            acc[0][0] = MFMA32(a0[s], b0[s], acc[0][0]);                                \
            acc[1][0] = MFMA32(a1[s], b0[s], acc[1][0]);                                \
        }                                                                               \
        __builtin_amdgcn_s_setprio(0); PBAR();                                          \
        /* ph2: read B j=1 (4); stage A(T+2)-h0; MFMA (i0,i1)xj1 */                     \
        _Pragma("unroll") for (int s = 0; s < 4; ++s)                                   \
            b1[s] = *(const short8*)(pB + 128 * 64 + cs[s] * 8);                        \
        if (DO2) { ST_A((BUF), 0, 0, (T) + 2); ST_A((BUF), 0, 1, (T) + 2); }            \
        PBAR();                                                                         \
        __builtin_amdgcn_s_setprio(1);                                                  \
        _Pragma("unroll") for (int s = 0; s < 4; ++s) {                                 \
            acc[0][1] = MFMA32(a0[s], b1[s], acc[0][1]);                                \
            acc[1][1] = MFMA32(a1[s], b1[s], acc[1][1]);                                \
        }                                                                               \
        __builtin_amdgcn_s_setprio(0); PBAR();                                          \
        /* ph3: read A i=2,3 (8); stage B(T+2)-h0; MFMA (i2,i3)xj0 */                   \
        _Pragma("unroll") for (int s = 0; s < 4; ++s) {                                 \
            a0[s] = *(const short8*)(pA + 128 * 64 + cs[s] * 8);                        \
            a1[s] = *(const short8*)(pA + 192 * 64 + cs[s] * 8);                        \
        }                                                                               \
        if (DO2) { ST_B((BUF), 0, 0, (T) + 2); ST_B((BUF), 0, 1, (T) + 2); }            \
        PBAR();                                                                         \
        __builtin_amdgcn_s_setprio(1);                                                  \
        _Pragma("unroll") for (int s = 0; s < 4; ++s) {                                 \
            acc[2][0] = MFMA32(a0[s], b0[s], acc[2][0]);                                \
            acc[3][0] = MFMA32(a1[s], b0[s], acc[3][0]);                                \
        }                                                                               \
        __builtin_amdgcn_s_setprio(0); PBAR();                                          \
        /* ph4: register-only; stage B(T+2)-h1; MFMA (i2,i3)xj1 */                      \
        if (DO2) { ST_B((BUF), 1, 0, (T) + 2); ST_B((BUF), 1, 1, (T) + 2); }            \
        __builtin_amdgcn_s_setprio(1);                                                  \
        _Pragma("unroll") for (int s = 0; s < 4; ++s) {                                 \
            acc[2][1] = MFMA32(a0[s], b1[s], acc[2][1]);                                \
            acc[3][1] = MFMA32(a1[s], b1[s], acc[3][1]);                                \
        }                                                                               \
        __builtin_amdgcn_s_setprio(0);                                                  \
    } while (0)

__global__ __launch_bounds__(512, 2) void gemm8_kernel(const unsigned short* __restrict__ Acat,
                                                       const unsigned short* __restrict__ Bt,
                                                       float* __restrict__ C) {
    __shared__ unsigned short lds[65536];   // 128 KiB: 2 buf x (A 256x64 + B 256x64) bf16

    // grid = 102 mtiles * 8 ntiles = 816 (816 % 8 == 0 -> bijective XCD swizzle)
    int wg  = blockIdx.x;
    int swz = (wg & 7) * 102 + (wg >> 3);
    int mt  = swz >> 3, nt = swz & 7;
    int m0  = mt * 256, n0 = nt * 256;

    int tid = threadIdx.x;
    int l   = tid & 63;
    int w   = tid >> 6;          // wave 0..7
    int wm  = w >> 2;            // 0..1
    int wn  = w & 3;             // 0..3
    int r32 = l & 31;
    int hi  = l >> 5;
    int e   = l & 7;
    int cs[4] = { (0 + hi) ^ e, (2 + hi) ^ e, (4 + hi) ^ e, (6 + hi) ^ e };

    // per-thread pre-swizzled global stage sources (linear gload_lds dest)
    int srow = tid >> 3;
    int sq   = (tid & 7) ^ (srow & 7);
    const unsigned short* aSt = Acat + (long)(m0 + srow) * K_DIM + sq * 8;
    const unsigned short* bSt = Bt   + (long)(n0 + srow) * K_DIM + sq * 8;

    f32x16 acc[4][2] = {};

    // prologue: tile0 full (8) + tile1 A0,B0,B1 (6); wait tile0 (vmcnt 6)
    ST_A(0, 0, 0, 0); ST_A(0, 0, 1, 0); ST_A(0, 1, 0, 0); ST_A(0, 1, 1, 0);
    ST_B(0, 0, 0, 0); ST_B(0, 0, 1, 0); ST_B(0, 1, 0, 0); ST_B(0, 1, 1, 0);
    ST_A(1, 0, 0, 1); ST_A(1, 0, 1, 1);
    ST_B(1, 0, 0, 1); ST_B(1, 0, 1, 1); ST_B(1, 1, 0, 1); ST_B(1, 1, 1, 1);
    VMC(6); PBAR();

    // main loop: 32 K-tiles, 2 per iteration
#pragma unroll 1
    for (int t = 0; t < 30; t += 2) {
        TILE(0, t, 1, 1);     VMC(6); PBAR();
        TILE(1, t + 1, 1, 1); VMC(6); PBAR();
    }
    TILE(0, 30, 1, 0); VMC(0); PBAR();
    TILE(1, 31, 0, 0);

    // epilogue: 32x32 C/D layout col=lane&31, row=(q&3)+8*(q>>2)+4*(lane>>5)
    int orow = m0 + wm * 32 + 4 * hi;
    int ocol = n0 + wn * 32 + r32;
#pragma unroll
    for (int i = 0; i < 4; ++i)
#pragma unroll
        for (int j = 0; j < 2; ++j)
#pragma unroll
            for (int q = 0; q < 16; ++q)
                C[(long)(orow + i * 64 + (q & 3) + 8 * (q >> 2)) * N_DIM +
                  (ocol + j * 128)] = acc[i][j][q];
}

// ---------- fallback: correct (slow) fp32 tiled GEMM, used only if ws too small ----------
__global__ void naive_gemm_kernel(const float* __restrict__ A, const float* __restrict__ B,
                                  float* __restrict__ C, int M) {
    __shared__ float As[16][16];
    __shared__ float Bs[16][17];
    int tx = threadIdx.x, ty = threadIdx.y;
    int row = blockIdx.y * 16 + ty;
    int col = blockIdx.x * 16 + tx;
    float s = 0.f;
    for (int k0 = 0; k0 < K_DIM; k0 += 16) {
        As[ty][tx] = A[(long)row * K_DIM + k0 + tx];
        Bs[ty][tx] = B[(long)(k0 + ty) * N_DIM + col];
        __syncthreads();
#pragma unroll
        for (int t = 0; t < 16; ++t) s += As[ty][t] * Bs[t][tx];
        __syncthreads();
    }
    C[(long)row * N_DIM + col] = s;
}

// ---------- host launcher ----------
extern "C" void kernel_launch(void* const* d_in, const int* in_sizes, int n_in,
                              void* d_out, int out_size, void* d_ws, size_t ws_size,
                              hipStream_t stream) {
    static const int g_m[N_GROUPS]   = {4096, 2048, 1024, 8192, 512, 3072, 6144, 1024};
    static const int g_off[N_GROUPS] = {0, 4096, 6144, 7168, 15360, 15872, 18944, 25088};

    float* C = (float*)d_out;
    const size_t need = ((size_t)M_TOTAL * K_DIM + (size_t)N_DIM * K_DIM) * 2;

    if (ws_size >= need) {
        unsigned short* Acat = (unsigned short*)d_ws;
        unsigned short* Bt   = Acat + (size_t)M_TOTAL * K_DIM;

        cvt_all<<<64 + M_TOTAL / 16, 256, 0, stream>>>(
            (const float*)d_in[0], (const float*)d_in[1], (const float*)d_in[2],
            (const float*)d_in[3], (const float*)d_in[4], (const float*)d_in[5],
            (const float*)d_in[6], (const float*)d_in[7], (const float*)d_in[8],
            Acat, Bt);

        gemm8_kernel<<<(M_TOTAL / 256) * (N_DIM / 256), 512, 0, stream>>>(Acat, Bt, C);
    } else {
        for (int g = 0; g < N_GROUPS; ++g)
            naive_gemm_kernel<<<dim3(N_DIM / 16, g_m[g] / 16), dim3(16, 16), 0, stream>>>(
                (const float*)d_in[g], (const float*)d_in[8], C + (size_t)g_off[g] * N_DIM,
                g_m[g]);
    }
}